// Round 6
// baseline (241.099 us; speedup 1.0000x reference)
//
#include <hip/hip_runtime.h>

#define BB 4
#define CIN 256
#define CO 64
#define HW_ 4096
#define NSPLIT 8
#define DCHUNK (HW_ / NSPLIT)

typedef __attribute__((ext_vector_type(8))) short short8;
typedef __attribute__((ext_vector_type(4))) float f32x4;

__device__ inline unsigned short f2bf(float f) {
  union { float f; unsigned u; } x; x.f = f;
  unsigned r = x.u + 0x7fffu + ((x.u >> 16) & 1u);  // RNE
  return (unsigned short)(r >> 16);
}
__device__ inline float bf2f(unsigned short h) {
  union { unsigned u; float f; } x; x.u = ((unsigned)h) << 16;
  return x.f;
}

// ---------------------------------------------------------------------------
// K1: QKV projection as MFMA GEMM. One block = one of {q,k,v} x 64-pos chunk.
// ---------------------------------------------------------------------------
__global__ __launch_bounds__(256, 3) void qkv_kernel(
    const float* __restrict__ x,
    const float* __restrict__ wq, const float* __restrict__ bq,
    const float* __restrict__ wk, const float* __restrict__ bk,
    const float* __restrict__ wv, const float* __restrict__ bv,
    unsigned short* __restrict__ qT, unsigned short* __restrict__ kT,
    unsigned short* __restrict__ v)
{
  const int b = blockIdx.z;
  const int which = blockIdx.y;       // 0=q, 1=k, 2=v
  const int n0 = blockIdx.x * 64;     // position base
  const int tid = threadIdx.x;
  const int w = tid >> 6, lane = tid & 63;
  const int lq = lane & 15, quad = lane >> 4;

  const float* W  = (which == 0) ? wq : (which == 1) ? wk : wv;
  const float* Bb = (which == 0) ? bq : (which == 1) ? bk : bv;

  __shared__ unsigned short w_lds[64 * 256];   // 32 KB, [m][k] bf16 swizzled
  unsigned char* wbytes = reinterpret_cast<unsigned char*>(w_lds);

#pragma unroll
  for (int i = 0; i < 16; ++i) {
    int L = i * 256 + tid;
    int row = L >> 6, col4 = L & 63;
    float4 w4 = *reinterpret_cast<const float4*>(&W[row * 256 + col4 * 4]);
    ushort4 p;
    p.x = f2bf(w4.x); p.y = f2bf(w4.y); p.z = f2bf(w4.z); p.w = f2bf(w4.w);
    int addr = (row * 512 + col4 * 8) ^ ((row & 7) << 4);
    *reinterpret_cast<ushort4*>(wbytes + addr) = p;
  }
  __syncthreads();

  const int n = n0 + w * 16 + lq;
  const float* xb = x + (size_t)b * CIN * HW_ + n;

  const f32x4 zero = {0.f, 0.f, 0.f, 0.f};
  f32x4 acc[4];
#pragma unroll
  for (int mt = 0; mt < 4; ++mt) acc[mt] = zero;

  for (int ks = 0; ks < 8; ++ks) {
    float xv[8];
#pragma unroll
    for (int j = 0; j < 8; ++j)
      xv[j] = xb[(size_t)(ks * 32 + quad * 8 + j) * HW_];
    short8 bhi, blo;
#pragma unroll
    for (int j = 0; j < 8; ++j) {
      unsigned short h = f2bf(xv[j]);
      bhi[j] = (short)h;
      blo[j] = (short)f2bf(xv[j] - bf2f(h));
    }
#pragma unroll
    for (int mt = 0; mt < 4; ++mt) {
      int addr = ((mt * 16 + lq) * 512 + ks * 64 + quad * 16) ^ ((lq & 7) << 4);
      short8 af = *reinterpret_cast<const short8*>(wbytes + addr);
      acc[mt] = __builtin_amdgcn_mfma_f32_16x16x32_bf16(af, bhi, acc[mt], 0, 0, 0);
      acc[mt] = __builtin_amdgcn_mfma_f32_16x16x32_bf16(af, blo, acc[mt], 0, 0, 0);
    }
  }

  float4 bias4[4];
#pragma unroll
  for (int mt = 0; mt < 4; ++mt)
    bias4[mt] = *reinterpret_cast<const float4*>(&Bb[mt * 16 + quad * 4]);

  if (which < 2) {
    unsigned short* outp = ((which == 0) ? qT : kT) + ((size_t)b * HW_ + n) * 64;
#pragma unroll
    for (int mt = 0; mt < 4; ++mt) {
      ushort4 p;
      p.x = f2bf(acc[mt][0] + bias4[mt].x);
      p.y = f2bf(acc[mt][1] + bias4[mt].y);
      p.z = f2bf(acc[mt][2] + bias4[mt].z);
      p.w = f2bf(acc[mt][3] + bias4[mt].w);
      *reinterpret_cast<ushort4*>(&outp[mt * 16 + quad * 4]) = p;
    }
  } else {
#pragma unroll
    for (int mt = 0; mt < 4; ++mt) {
      float bb[4] = {bias4[mt].x, bias4[mt].y, bias4[mt].z, bias4[mt].w};
#pragma unroll
      for (int r = 0; r < 4; ++r)
        v[((size_t)b * CO + mt * 16 + quad * 4 + r) * HW_ + n] = f2bf(acc[mt][r] + bb[r]);
    }
  }
}

// ---------------------------------------------------------------------------
// K2a: partial softmax stats. Barrier-free: K A-fragments direct from global
// (wave-id-independent addresses -> L1 broadcast across waves). No LDS.
// ---------------------------------------------------------------------------
__global__ __launch_bounds__(256, 6) void stats_kernel(
    const unsigned short* __restrict__ qT,
    const unsigned short* __restrict__ kT,
    float2* __restrict__ parts)
{
  const int b = blockIdx.z;
  const int split = blockIdx.y;
  const int dt0 = blockIdx.x * 64;
  const int tid = threadIdx.x;
  const int wid = tid >> 6, lane = tid & 63;
  const int lq = lane & 15, quad = lane >> 4;

  const size_t base = (size_t)b * HW_ * CO;
  const int d = dt0 + wid * 16 + lq;
  const short8 qf0 = *reinterpret_cast<const short8*>(&qT[base + (size_t)d * 64 + quad * 8]);
  const short8 qf1 = *reinterpret_cast<const short8*>(&qT[base + (size_t)d * 64 + 32 + quad * 8]);

  float m_run = -3.0e38f, l_run = 0.f;
  const char* kT_bytes = reinterpret_cast<const char*>(kT) + base * 2;

  const int e_beg = split * DCHUNK;
#pragma unroll 2
  for (int e0 = e_beg; e0 < e_beg + DCHUNK; e0 += 64) {
    const f32x4 zero = {0.f, 0.f, 0.f, 0.f};
    f32x4 sT[4];
#pragma unroll
    for (int mt = 0; mt < 4; ++mt) sT[mt] = zero;
#pragma unroll
    for (int s = 0; s < 2; ++s)
#pragma unroll
      for (int mt = 0; mt < 4; ++mt) {
        const short8 af = *reinterpret_cast<const short8*>(
            kT_bytes + (size_t)(e0 + mt * 16 + lq) * 128 + s * 64 + quad * 16);
        sT[mt] = __builtin_amdgcn_mfma_f32_16x16x32_bf16(af, s ? qf1 : qf0, sT[mt], 0, 0, 0);
      }

    float tmax = -3.0e38f;
#pragma unroll
    for (int mt = 0; mt < 4; ++mt)
#pragma unroll
      for (int r = 0; r < 4; ++r) tmax = fmaxf(tmax, sT[mt][r]);
    tmax = fmaxf(tmax, __shfl_xor(tmax, 16));
    tmax = fmaxf(tmax, __shfl_xor(tmax, 32));
    float m_new = fmaxf(m_run, tmax);
    float corr = __expf(m_run - m_new);
    float lsum = 0.f;
#pragma unroll
    for (int mt = 0; mt < 4; ++mt)
#pragma unroll
      for (int r = 0; r < 4; ++r) lsum += __expf(sT[mt][r] - m_new);
    lsum += __shfl_xor(lsum, 16);
    lsum += __shfl_xor(lsum, 32);
    l_run = l_run * corr + lsum;
    m_run = m_new;
  }
  if (quad == 0)
    parts[((size_t)b * HW_ + d) * NSPLIT + split] = make_float2(m_run, l_run);
}

// ---------------------------------------------------------------------------
// K2b: merge per-split stats -> ml[d] = M + log sum l_i exp(m_i - M). Exact.
// ---------------------------------------------------------------------------
__global__ __launch_bounds__(256) void combine_kernel(
    const float2* __restrict__ parts, float* __restrict__ ml)
{
  const int r = blockIdx.x * 256 + threadIdx.x;
  float2 p[NSPLIT];
#pragma unroll
  for (int i = 0; i < NSPLIT; ++i) p[i] = parts[(size_t)r * NSPLIT + i];
  float M = p[0].x;
#pragma unroll
  for (int i = 1; i < NSPLIT; ++i) M = fmaxf(M, p[i].x);
  float L = 0.f;
#pragma unroll
  for (int i = 0; i < NSPLIT; ++i) L += p[i].y * __expf(p[i].x - M);
  ml[r] = M + __logf(L);
}

// ---------------------------------------------------------------------------
// K3: partial o[c,e] over a d-chunk. Barrier-free main loop: Q/V fragments
// direct from global (wave-uniform addrs -> L1 broadcast), ml per-lane from
// global, P through per-wave LDS only. Epilogue: LDS transpose -> dense
// 128B-line NT stores (kills write amplification).
// ---------------------------------------------------------------------------
__global__ __launch_bounds__(256, 6) void apply_kernel(
    const unsigned short* __restrict__ qT,
    const unsigned short* __restrict__ kT,
    const unsigned short* __restrict__ vv,
    const float* __restrict__ ml,
    unsigned short* __restrict__ Opart)
{
  const int b = blockIdx.z;
  const int split = blockIdx.y;
  const int et0 = blockIdx.x * 64;
  const int tid = threadIdx.x;
  const int wid = tid >> 6, lane = tid & 63;
  const int lq = lane & 15, quad = lane >> 4;

  __shared__ __align__(16) unsigned short p_lds[4][16][72];  // per-wave [16 e][64 d + pad]
  __shared__ __align__(16) unsigned short o_lds[64][64];     // [c][e] epilogue tile

  const size_t base = (size_t)b * HW_ * CO;
  const int e = et0 + wid * 16 + lq;
  const short8 kf0 = *reinterpret_cast<const short8*>(&kT[base + (size_t)e * 64 + quad * 8]);
  const short8 kf1 = *reinterpret_cast<const short8*>(&kT[base + (size_t)e * 64 + 32 + quad * 8]);

  const f32x4 zero = {0.f, 0.f, 0.f, 0.f};
  f32x4 Of[4];
#pragma unroll
  for (int ct = 0; ct < 4; ++ct) Of[ct] = zero;

  const char* qT_bytes = reinterpret_cast<const char*>(qT) + base * 2;
  const char* v_bytes = reinterpret_cast<const char*>(vv) + base * 2;
  const float* mlb = ml + (size_t)b * HW_;

  const int d_beg = split * DCHUNK;
#pragma unroll 2
  for (int dt = d_beg; dt < d_beg + DCHUNK; dt += 64) {
    // T[e_loc, d_loc] = S[d, e]; Q B-fragments direct from global
    f32x4 T[4];
#pragma unroll
    for (int nt = 0; nt < 4; ++nt) T[nt] = zero;
#pragma unroll
    for (int s = 0; s < 2; ++s)
#pragma unroll
      for (int nt = 0; nt < 4; ++nt) {
        const short8 qfr = *reinterpret_cast<const short8*>(
            qT_bytes + (size_t)(dt + nt * 16 + lq) * 128 + s * 64 + quad * 16);
        T[nt] = __builtin_amdgcn_mfma_f32_16x16x32_bf16(s ? kf1 : kf0, qfr, T[nt], 0, 0, 0);
      }
    // P = exp(S - ml[d]) -> per-wave LDS [e_loc][d_loc] bf16
#pragma unroll
    for (int nt = 0; nt < 4; ++nt) {
      float mld = mlb[dt + nt * 16 + lq];
#pragma unroll
      for (int r = 0; r < 4; ++r) {
        float p = __expf(T[nt][r] - mld);
        p_lds[wid][quad * 4 + r][nt * 16 + lq] = f2bf(p);
      }
    }
    // PV: O[c, e] += V[c, d] * P[d, e]; V A-fragments direct from global
#pragma unroll
    for (int s = 0; s < 2; ++s) {
      short8 pf = *reinterpret_cast<const short8*>(
          reinterpret_cast<const unsigned char*>(&p_lds[wid][0][0]) + lq * 144 + s * 64 + quad * 16);
#pragma unroll
      for (int ct = 0; ct < 4; ++ct) {
        const short8 vf = *reinterpret_cast<const short8*>(
            v_bytes + (size_t)(ct * 16 + lq) * 8192 + dt * 2 + s * 64 + quad * 16);
        Of[ct] = __builtin_amdgcn_mfma_f32_16x16x32_bf16(vf, pf, Of[ct], 0, 0, 0);
      }
    }
  }

  // epilogue: transpose via LDS, then dense 128B-line NT stores
#pragma unroll
  for (int ct = 0; ct < 4; ++ct)
#pragma unroll
    for (int r = 0; r < 4; ++r)
      o_lds[ct * 16 + quad * 4 + r][wid * 16 + lq] = f2bf(Of[ct][r]);
  __syncthreads();
  {
    const int c = tid >> 2, e0 = (tid & 3) * 16;
    f32x4 w0 = *reinterpret_cast<const f32x4*>(&o_lds[c][e0]);
    f32x4 w1 = *reinterpret_cast<const f32x4*>(&o_lds[c][e0 + 8]);
    unsigned short* dst = &Opart[((size_t)(b * NSPLIT + split) * CO + c) * HW_ + et0 + e0];
    __builtin_nontemporal_store(w0, reinterpret_cast<f32x4*>(dst));
    __builtin_nontemporal_store(w1, reinterpret_cast<f32x4*>(dst + 8));
  }
}

// ---------------------------------------------------------------------------
// K4: out[f, d] = sum_c wo[f, c] * (sum_s Opart_bf16[s][c, d]) + bo[f]
// ---------------------------------------------------------------------------
__global__ __launch_bounds__(256) void outproj_kernel(
    const unsigned short* __restrict__ Opart, const float* __restrict__ wo,
    const float* __restrict__ bo, float* __restrict__ out)
{
  const int b = blockIdx.z;
  const int f0 = blockIdx.y * 32;
  const int d = blockIdx.x * 256 + threadIdx.x;
  float acc[32];
#pragma unroll
  for (int j = 0; j < 32; ++j) acc[j] = bo[f0 + j];
  const unsigned short* Ob = Opart + (size_t)b * NSPLIT * CO * HW_;
#pragma unroll 2
  for (int c = 0; c < CO; ++c) {
    float ov = 0.f;
#pragma unroll
    for (int s = 0; s < NSPLIT; ++s) ov += bf2f(Ob[(size_t)(s * CO + c) * HW_ + d]);
#pragma unroll
    for (int j = 0; j < 32; ++j)
      acc[j] = fmaf(wo[(size_t)(f0 + j) * CO + c], ov, acc[j]);
  }
#pragma unroll
  for (int j = 0; j < 32; ++j)
    out[((size_t)b * CIN + f0 + j) * HW_ + d] = acc[j];
}

extern "C" void kernel_launch(void* const* d_in, const int* in_sizes, int n_in,
                              void* d_out, int out_size, void* d_ws, size_t ws_size,
                              hipStream_t stream) {
  const float* x  = (const float*)d_in[0];
  const float* wq = (const float*)d_in[1];
  const float* bq = (const float*)d_in[2];
  const float* wk = (const float*)d_in[3];
  const float* bk = (const float*)d_in[4];
  const float* wv = (const float*)d_in[5];
  const float* bv = (const float*)d_in[6];
  const float* wo = (const float*)d_in[7];
  const float* bo = (const float*)d_in[8];
  float* out = (float*)d_out;

  char* ws = (char*)d_ws;
  unsigned short* qT    = (unsigned short*)(ws);               // 2 MB  [b][4096][64] bf16
  unsigned short* kT    = (unsigned short*)(ws + (2u << 20));  // 2 MB  [b][4096][64] bf16
  unsigned short* v     = (unsigned short*)(ws + (4u << 20));  // 2 MB  [b][64][4096] bf16
  unsigned short* Opart = (unsigned short*)(ws + (6u << 20));  // 16 MB [b][8][64][4096] bf16
  float* ml             = (float*)(ws + (23u << 20));          // 64 KB [b][4096] f32
  float2* parts         = (float2*)(ws + (24u << 20));         // 1 MB  [b][4096][8] float2

  qkv_kernel<<<dim3(64, 3, 4), 256, 0, stream>>>(x, wq, bq, wk, bk, wv, bv, qT, kT, v);
  stats_kernel<<<dim3(64, NSPLIT, 4), 256, 0, stream>>>(qT, kT, parts);
  combine_kernel<<<dim3(BB * HW_ / 256), 256, 0, stream>>>(parts, ml);
  apply_kernel<<<dim3(64, NSPLIT, 4), 256, 0, stream>>>(qT, kT, v, ml, Opart);
  outproj_kernel<<<dim3(16, 8, 4), 256, 0, stream>>>(Opart, wo, bo, out);
}

// Round 7
// 129.193 us; speedup vs baseline: 1.8662x; 1.8662x over previous
//
#include <hip/hip_runtime.h>

#define BB 4
#define CIN 256
#define CO 64
#define HW_ 4096
#define SPLIT_A 8               // apply: d-split
#define SPLIT_S 8               // stats: e-split
#define DCHUNK_A (HW_ / SPLIT_A)   // 512
#define ECHUNK_S (HW_ / SPLIT_S)   // 512

typedef __attribute__((ext_vector_type(8))) short short8;
typedef __attribute__((ext_vector_type(4))) float f32x4;

__device__ inline unsigned short f2bf(float f) {
  union { float f; unsigned u; } x; x.f = f;
  unsigned r = x.u + 0x7fffu + ((x.u >> 16) & 1u);  // RNE
  return (unsigned short)(r >> 16);
}
__device__ inline float bf2f(unsigned short h) {
  union { unsigned u; float f; } x; x.u = ((unsigned)h) << 16;
  return x.f;
}

// ---------------------------------------------------------------------------
// K1: QKV projection as MFMA GEMM. One block = one of {q,k,v} x 64-pos chunk.
// ---------------------------------------------------------------------------
__global__ __launch_bounds__(256, 3) void qkv_kernel(
    const float* __restrict__ x,
    const float* __restrict__ wq, const float* __restrict__ bq,
    const float* __restrict__ wk, const float* __restrict__ bk,
    const float* __restrict__ wv, const float* __restrict__ bv,
    unsigned short* __restrict__ qT, unsigned short* __restrict__ kT,
    unsigned short* __restrict__ v)
{
  const int b = blockIdx.z;
  const int which = blockIdx.y;       // 0=q, 1=k, 2=v
  const int n0 = blockIdx.x * 64;     // position base
  const int tid = threadIdx.x;
  const int w = tid >> 6, lane = tid & 63;
  const int lq = lane & 15, quad = lane >> 4;

  const float* W  = (which == 0) ? wq : (which == 1) ? wk : wv;
  const float* Bb = (which == 0) ? bq : (which == 1) ? bk : bv;

  __shared__ unsigned short w_lds[64 * 256];   // 32 KB, [m][k] bf16 swizzled
  unsigned char* wbytes = reinterpret_cast<unsigned char*>(w_lds);

#pragma unroll
  for (int i = 0; i < 16; ++i) {
    int L = i * 256 + tid;
    int row = L >> 6, col4 = L & 63;
    float4 w4 = *reinterpret_cast<const float4*>(&W[row * 256 + col4 * 4]);
    ushort4 p;
    p.x = f2bf(w4.x); p.y = f2bf(w4.y); p.z = f2bf(w4.z); p.w = f2bf(w4.w);
    int addr = (row * 512 + col4 * 8) ^ ((row & 7) << 4);
    *reinterpret_cast<ushort4*>(wbytes + addr) = p;
  }
  __syncthreads();

  const int n = n0 + w * 16 + lq;
  const float* xb = x + (size_t)b * CIN * HW_ + n;

  const f32x4 zero = {0.f, 0.f, 0.f, 0.f};
  f32x4 acc[4];
#pragma unroll
  for (int mt = 0; mt < 4; ++mt) acc[mt] = zero;

  for (int ks = 0; ks < 8; ++ks) {
    float xv[8];
#pragma unroll
    for (int j = 0; j < 8; ++j)
      xv[j] = xb[(size_t)(ks * 32 + quad * 8 + j) * HW_];
    short8 bhi, blo;
#pragma unroll
    for (int j = 0; j < 8; ++j) {
      unsigned short h = f2bf(xv[j]);
      bhi[j] = (short)h;
      blo[j] = (short)f2bf(xv[j] - bf2f(h));
    }
#pragma unroll
    for (int mt = 0; mt < 4; ++mt) {
      int addr = ((mt * 16 + lq) * 512 + ks * 64 + quad * 16) ^ ((lq & 7) << 4);
      short8 af = *reinterpret_cast<const short8*>(wbytes + addr);
      acc[mt] = __builtin_amdgcn_mfma_f32_16x16x32_bf16(af, bhi, acc[mt], 0, 0, 0);
      acc[mt] = __builtin_amdgcn_mfma_f32_16x16x32_bf16(af, blo, acc[mt], 0, 0, 0);
    }
  }

  float4 bias4[4];
#pragma unroll
  for (int mt = 0; mt < 4; ++mt)
    bias4[mt] = *reinterpret_cast<const float4*>(&Bb[mt * 16 + quad * 4]);

  if (which < 2) {
    unsigned short* outp = ((which == 0) ? qT : kT) + ((size_t)b * HW_ + n) * 64;
#pragma unroll
    for (int mt = 0; mt < 4; ++mt) {
      ushort4 p;
      p.x = f2bf(acc[mt][0] + bias4[mt].x);
      p.y = f2bf(acc[mt][1] + bias4[mt].y);
      p.z = f2bf(acc[mt][2] + bias4[mt].z);
      p.w = f2bf(acc[mt][3] + bias4[mt].w);
      *reinterpret_cast<ushort4*>(&outp[mt * 16 + quad * 4]) = p;
    }
  } else {
#pragma unroll
    for (int mt = 0; mt < 4; ++mt) {
      float bb[4] = {bias4[mt].x, bias4[mt].y, bias4[mt].z, bias4[mt].w};
#pragma unroll
      for (int r = 0; r < 4; ++r)
        v[((size_t)b * CO + mt * 16 + quad * 4 + r) * HW_ + n] = f2bf(acc[mt][r] + bb[r]);
    }
  }
}

// ---------------------------------------------------------------------------
// K2a: partial softmax stats. 8-wave block owns 128 d rows; step = 128 e
// staged in LDS (XOR-swizzled) with reg-prefetch of next tile (T14).
// ---------------------------------------------------------------------------
__global__ __launch_bounds__(512, 2) void stats_kernel(
    const unsigned short* __restrict__ qT,
    const unsigned short* __restrict__ kT,
    float2* __restrict__ parts)
{
  const int b = blockIdx.z;
  const int split = blockIdx.y;
  const int dt0 = blockIdx.x * 128;
  const int tid = threadIdx.x;
  const int w = tid >> 6, lane = tid & 63;
  const int lq = lane & 15, quad = lane >> 4;

  __shared__ __align__(16) unsigned char k_lds[128 * 128];  // [128 e][64 c] bf16 swz

  const size_t base = (size_t)b * HW_ * CO;
  const int d = dt0 + w * 16 + lq;
  const short8 qf0 = *reinterpret_cast<const short8*>(&qT[base + (size_t)d * 64 + quad * 8]);
  const short8 qf1 = *reinterpret_cast<const short8*>(&qT[base + (size_t)d * 64 + 32 + quad * 8]);

  float m_run = -3.0e38f, l_run = 0.f;
  const char* kT_bytes = reinterpret_cast<const char*>(kT) + base * 2;

  const int e_beg = split * ECHUNK_S;
  float4 kreg[2];
  auto load_k = [&](int e0) {
#pragma unroll
    for (int i = 0; i < 2; ++i) {
      int L = (i * 512 + tid) * 16;
      int row = L >> 7, colb = L & 127;
      kreg[i] = *reinterpret_cast<const float4*>(kT_bytes + (size_t)(e0 + row) * 128 + colb);
    }
  };
  load_k(e_beg);

  for (int e0 = e_beg; e0 < e_beg + ECHUNK_S; e0 += 128) {
    __syncthreads();
#pragma unroll
    for (int i = 0; i < 2; ++i) {
      int L = (i * 512 + tid) * 16;
      int row = L >> 7, colb = L & 127;
      *reinterpret_cast<float4*>(k_lds + row * 128 + (colb ^ ((row & 7) << 4))) = kreg[i];
    }
    __syncthreads();
    if (e0 + 128 < e_beg + ECHUNK_S) load_k(e0 + 128);

    const f32x4 zero = {0.f, 0.f, 0.f, 0.f};
    f32x4 sT[8];
#pragma unroll
    for (int et = 0; et < 8; ++et) sT[et] = zero;
#pragma unroll
    for (int s = 0; s < 2; ++s)
#pragma unroll
      for (int et = 0; et < 8; ++et) {
        int row = et * 16 + lq;
        const short8 af = *reinterpret_cast<const short8*>(
            k_lds + row * 128 + ((s * 64 + quad * 16) ^ ((row & 7) << 4)));
        sT[et] = __builtin_amdgcn_mfma_f32_16x16x32_bf16(af, s ? qf1 : qf0, sT[et], 0, 0, 0);
      }

    float tmax = -3.0e38f;
#pragma unroll
    for (int et = 0; et < 8; ++et)
#pragma unroll
      for (int r = 0; r < 4; ++r) tmax = fmaxf(tmax, sT[et][r]);
    tmax = fmaxf(tmax, __shfl_xor(tmax, 16));
    tmax = fmaxf(tmax, __shfl_xor(tmax, 32));
    float m_new = fmaxf(m_run, tmax);
    float corr = __expf(m_run - m_new);
    float lsum = 0.f;
#pragma unroll
    for (int et = 0; et < 8; ++et)
#pragma unroll
      for (int r = 0; r < 4; ++r) lsum += __expf(sT[et][r] - m_new);
    lsum += __shfl_xor(lsum, 16);
    lsum += __shfl_xor(lsum, 32);
    l_run = l_run * corr + lsum;
    m_run = m_new;
  }
  if (quad == 0)
    parts[((size_t)b * HW_ + d) * SPLIT_S + split] = make_float2(m_run, l_run);
}

// ---------------------------------------------------------------------------
// K2b: merge per-split stats -> ml[d] = M + log sum l_i exp(m_i - M). Exact.
// ---------------------------------------------------------------------------
__global__ __launch_bounds__(256) void combine_kernel(
    const float2* __restrict__ parts, float* __restrict__ ml)
{
  const int r = blockIdx.x * 256 + threadIdx.x;
  float2 p[SPLIT_S];
#pragma unroll
  for (int i = 0; i < SPLIT_S; ++i) p[i] = parts[(size_t)r * SPLIT_S + i];
  float M = p[0].x;
#pragma unroll
  for (int i = 1; i < SPLIT_S; ++i) M = fmaxf(M, p[i].x);
  float L = 0.f;
#pragma unroll
  for (int i = 0; i < SPLIT_S; ++i) L += p[i].y * __expf(p[i].x - M);
  ml[r] = M + __logf(L);
}

// ---------------------------------------------------------------------------
// K3: partial o[c,e]. 8-wave block owns 128 e; step = 128 d. Q/V tiles
// LDS-staged (swizzled) with reg-prefetch; P via per-wave LDS; epilogue
// LDS transpose -> dense 256B-row NT stores.
// ---------------------------------------------------------------------------
__global__ __launch_bounds__(512, 2) void apply_kernel(
    const unsigned short* __restrict__ qT,
    const unsigned short* __restrict__ kT,
    const unsigned short* __restrict__ vv,
    const float* __restrict__ ml,
    unsigned short* __restrict__ Opart)
{
  const int b = blockIdx.z;
  const int split = blockIdx.y;
  const int e0 = blockIdx.x * 128;
  const int tid = threadIdx.x;
  const int w = tid >> 6, lane = tid & 63;
  const int lq = lane & 15, quad = lane >> 4;

  __shared__ __align__(16) unsigned char q_lds[128 * 128];        // [128 d][64 c] swz
  __shared__ __align__(16) unsigned char v_lds[64 * 256];         // [64 c][128 d] swz
  __shared__ __align__(16) unsigned short p_lds[8][16][136];      // per-wave [16 e][128 d+pad]
  __shared__ float ml_lds[128];

  const size_t base = (size_t)b * HW_ * CO;
  const int e = e0 + w * 16 + lq;
  const short8 kf0 = *reinterpret_cast<const short8*>(&kT[base + (size_t)e * 64 + quad * 8]);
  const short8 kf1 = *reinterpret_cast<const short8*>(&kT[base + (size_t)e * 64 + 32 + quad * 8]);

  const f32x4 zero = {0.f, 0.f, 0.f, 0.f};
  f32x4 Of[4];
#pragma unroll
  for (int ct = 0; ct < 4; ++ct) Of[ct] = zero;

  const char* qT_bytes = reinterpret_cast<const char*>(qT) + base * 2;
  const char* v_bytes = reinterpret_cast<const char*>(vv) + base * 2;
  const float* mlb = ml + (size_t)b * HW_;

  const int d_beg = split * DCHUNK_A;
  float4 qreg[2], vreg[2];
  float mlv = 0.f;
  auto load_t = [&](int dt) {
#pragma unroll
    for (int i = 0; i < 2; ++i) {
      int L = (i * 512 + tid) * 16;
      int row = L >> 7, colb = L & 127;
      qreg[i] = *reinterpret_cast<const float4*>(qT_bytes + (size_t)(dt + row) * 128 + colb);
      int vrow = L >> 8, vcolb = L & 255;
      vreg[i] = *reinterpret_cast<const float4*>(v_bytes + (size_t)vrow * 8192 + dt * 2 + vcolb);
    }
    if (tid < 128) mlv = mlb[dt + tid];
  };
  load_t(d_beg);

  for (int dt = d_beg; dt < d_beg + DCHUNK_A; dt += 128) {
    __syncthreads();
#pragma unroll
    for (int i = 0; i < 2; ++i) {
      int L = (i * 512 + tid) * 16;
      int row = L >> 7, colb = L & 127;
      *reinterpret_cast<float4*>(q_lds + row * 128 + (colb ^ ((row & 7) << 4))) = qreg[i];
      int vrow = L >> 8, vcolb = L & 255;
      *reinterpret_cast<float4*>(v_lds + vrow * 256 + (vcolb ^ ((vrow & 15) << 4))) = vreg[i];
    }
    if (tid < 128) ml_lds[tid] = mlv;
    __syncthreads();
    if (dt + 128 < d_beg + DCHUNK_A) load_t(dt + 128);

    // QK: T[nt] holds S[d, e] for wave's 16 e x 128 d
    f32x4 T[8];
#pragma unroll
    for (int nt = 0; nt < 8; ++nt) T[nt] = zero;
#pragma unroll
    for (int s = 0; s < 2; ++s)
#pragma unroll
      for (int nt = 0; nt < 8; ++nt) {
        int row = nt * 16 + lq;
        const short8 qfr = *reinterpret_cast<const short8*>(
            q_lds + row * 128 + ((s * 64 + quad * 16) ^ ((row & 7) << 4)));
        T[nt] = __builtin_amdgcn_mfma_f32_16x16x32_bf16(s ? kf1 : kf0, qfr, T[nt], 0, 0, 0);
      }
    // P = exp(S - ml[d]) -> per-wave LDS [16 e][128 d] bf16
    unsigned short* pw = &p_lds[w][0][0];
#pragma unroll
    for (int nt = 0; nt < 8; ++nt) {
      float mld = ml_lds[nt * 16 + lq];
#pragma unroll
      for (int r = 0; r < 4; ++r) {
        float p = __expf(T[nt][r] - mld);
        pw[(quad * 4 + r) * 136 + nt * 16 + lq] = f2bf(p);
      }
    }
    // PV: O[c, e] += V[c, d] * P[d, e]
#pragma unroll
    for (int ks = 0; ks < 4; ++ks) {
      const short8 pf = *reinterpret_cast<const short8*>(
          reinterpret_cast<const unsigned char*>(pw) + lq * 272 + ks * 64 + quad * 16);
#pragma unroll
      for (int ct = 0; ct < 4; ++ct) {
        int row = ct * 16 + lq;
        const short8 vf = *reinterpret_cast<const short8*>(
            v_lds + row * 256 + ((ks * 64 + quad * 16) ^ ((row & 15) << 4)));
        Of[ct] = __builtin_amdgcn_mfma_f32_16x16x32_bf16(vf, pf, Of[ct], 0, 0, 0);
      }
    }
  }

  // epilogue: transpose via LDS (overlay q_lds), dense 256B-row NT stores
  __syncthreads();
  unsigned short* o_lds = reinterpret_cast<unsigned short*>(q_lds);  // [64 c][128 e]
#pragma unroll
  for (int ct = 0; ct < 4; ++ct)
#pragma unroll
    for (int r = 0; r < 4; ++r)
      o_lds[(ct * 16 + quad * 4 + r) * 128 + w * 16 + lq] = f2bf(Of[ct][r]);
  __syncthreads();
  {
    const int c = tid >> 3, ee = (tid & 7) * 16;
    f32x4 w0 = *reinterpret_cast<const f32x4*>(&o_lds[c * 128 + ee]);
    f32x4 w1 = *reinterpret_cast<const f32x4*>(&o_lds[c * 128 + ee + 8]);
    unsigned short* dst = &Opart[((size_t)(b * SPLIT_A + split) * CO + c) * HW_ + e0 + ee];
    __builtin_nontemporal_store(w0, reinterpret_cast<f32x4*>(dst));
    __builtin_nontemporal_store(w1, reinterpret_cast<f32x4*>(dst + 8));
  }
}

// ---------------------------------------------------------------------------
// K4: out[f, d] = sum_c wo[f, c] * (sum_s Opart_bf16[s][c, d]) + bo[f]
// ---------------------------------------------------------------------------
__global__ __launch_bounds__(256) void outproj_kernel(
    const unsigned short* __restrict__ Opart, const float* __restrict__ wo,
    const float* __restrict__ bo, float* __restrict__ out)
{
  const int b = blockIdx.z;
  const int f0 = blockIdx.y * 32;
  const int d = blockIdx.x * 256 + threadIdx.x;
  float acc[32];
#pragma unroll
  for (int j = 0; j < 32; ++j) acc[j] = bo[f0 + j];
  const unsigned short* Ob = Opart + (size_t)b * SPLIT_A * CO * HW_;
#pragma unroll 2
  for (int c = 0; c < CO; ++c) {
    float ov = 0.f;
#pragma unroll
    for (int s = 0; s < SPLIT_A; ++s) ov += bf2f(Ob[(size_t)(s * CO + c) * HW_ + d]);
#pragma unroll
    for (int j = 0; j < 32; ++j)
      acc[j] = fmaf(wo[(size_t)(f0 + j) * CO + c], ov, acc[j]);
  }
#pragma unroll
  for (int j = 0; j < 32; ++j)
    out[((size_t)b * CIN + f0 + j) * HW_ + d] = acc[j];
}

extern "C" void kernel_launch(void* const* d_in, const int* in_sizes, int n_in,
                              void* d_out, int out_size, void* d_ws, size_t ws_size,
                              hipStream_t stream) {
  const float* x  = (const float*)d_in[0];
  const float* wq = (const float*)d_in[1];
  const float* bq = (const float*)d_in[2];
  const float* wk = (const float*)d_in[3];
  const float* bk = (const float*)d_in[4];
  const float* wv = (const float*)d_in[5];
  const float* bv = (const float*)d_in[6];
  const float* wo = (const float*)d_in[7];
  const float* bo = (const float*)d_in[8];
  float* out = (float*)d_out;

  char* ws = (char*)d_ws;
  unsigned short* qT    = (unsigned short*)(ws);               // 2 MB  [b][4096][64] bf16
  unsigned short* kT    = (unsigned short*)(ws + (2u << 20));  // 2 MB  [b][4096][64] bf16
  unsigned short* v     = (unsigned short*)(ws + (4u << 20));  // 2 MB  [b][64][4096] bf16
  unsigned short* Opart = (unsigned short*)(ws + (6u << 20));  // 16 MB [b][8][64][4096] bf16
  float* ml             = (float*)(ws + (23u << 20));          // 64 KB [b][4096] f32
  float2* parts         = (float2*)(ws + (24u << 20));         // 1 MB  [b][4096][8] float2

  qkv_kernel<<<dim3(64, 3, 4), 256, 0, stream>>>(x, wq, bq, wk, bk, wv, bv, qT, kT, v);
  stats_kernel<<<dim3(32, SPLIT_S, 4), 512, 0, stream>>>(qT, kT, parts);
  combine_kernel<<<dim3(BB * HW_ / 256), 256, 0, stream>>>(parts, ml);
  apply_kernel<<<dim3(32, SPLIT_A, 4), 512, 0, stream>>>(qT, kT, v, ml, Opart);
  outproj_kernel<<<dim3(16, 8, 4), 256, 0, stream>>>(Opart, wo, bo, out);
}